// Round 6
// baseline (182.189 us; speedup 1.0000x reference)
//
#include <hip/hip_runtime.h>
#include <math.h>

// PizzaBurningEffect: out = clip(img * (1 - bm*(1-dark_scale_c)), 0, 1)
// bm = clip(max(ew_norm, max_s spot_s) * burn, 0, 1), shared across C=3 channels.
//
// R5 post-mortem: all variants pinned at ~59-60us, VALU 31% / HBM 31% / Occ 64%
// -> latency-bound with ~4-5k-cycle effective load latency (poison-fill drain
// congestion + possible load sinking). This round: occupancy 64->100% via
// __launch_bounds__(256,8) (VGPR<=64), named load regs issued first (low peak
// pressure so the scheduler keeps them hoisted), v_med3 clamps to trim VALU.

namespace {
constexpr int B = 32, C = 3, H = 512, W = 512, S = 8;
constexpr int PLANE = H * W;                            // 262144
constexpr int BLOCKS_PER_BATCH = PLANE / 8 / 256;       // 128 blocks/batch
constexpr float LOG2E = 1.4426950408889634f;
typedef float fvec4 __attribute__((ext_vector_type(4)));
}

__global__ __launch_bounds__(256, 8) void pizza_burn_kernel(
    const float* __restrict__ img,
    const float* __restrict__ u_xy,
    const float* __restrict__ u_radius,
    const float* __restrict__ u_intensity,
    const float* __restrict__ u_burn,
    float* __restrict__ out,
    const float ew_scale, const float ew_bias)
{
  // b is wave-uniform (derived from blockIdx only) -> spot params scalarize.
  const int b    = blockIdx.x >> 7;                         // 128 blocks per batch
  const int pix8 = ((blockIdx.x & 127) << 8) | threadIdx.x; // 0..32767
  const int h    = pix8 >> 6;             // 64 float8 per row of 512
  const int w0   = (pix8 & 63) << 3;      // starting column of this float8

  // Issue ALL 6 image loads up front (named regs, statically indexed):
  // 6 x global_load_dwordx4 in flight under the ~600-cycle mask computation.
  const size_t base = (size_t)b * (C * PLANE) + (size_t)h * W + w0;
  const fvec4 v0 = *reinterpret_cast<const fvec4*>(img + base);
  const fvec4 v1 = *reinterpret_cast<const fvec4*>(img + base + 4);
  const fvec4 v2 = *reinterpret_cast<const fvec4*>(img + base + PLANE);
  const fvec4 v3 = *reinterpret_cast<const fvec4*>(img + base + PLANE + 4);
  const fvec4 v4 = *reinterpret_cast<const fvec4*>(img + base + 2 * PLANE);
  const fvec4 v5 = *reinterpret_cast<const fvec4*>(img + base + 2 * PLANE + 4);

  const float delta = 2.0f / 511.0f;
  const float yc = fmaf((float)h, delta, -1.0f);
  const float y2 = yc * yc;

  // Per-batch spot params, folded for this row: lm_s(x) = nc_s*(xc-sx_s)^2 + cy_s,
  // cy_s = nc_s*(yc-sy_s)^2 + log2(si_s).  3 regs/spot, dead after mask phase.
  const float* uxy = u_xy        + (size_t)b * S * 2;
  const float* urd = u_radius    + (size_t)b * S;
  const float* uin = u_intensity + (size_t)b * S;
  float sx[S], nc[S], cy[S];
#pragma unroll
  for (int s = 0; s < S; ++s) {
    sx[s] = fmaf(2.0f, uxy[2 * s + 0], -1.0f);
    const float sy = fmaf(2.0f, uxy[2 * s + 1], -1.0f);
    const float r  = fmaf(0.15f, urd[s], 0.05f);
    nc[s] = (-0.5f * LOG2E) * __builtin_amdgcn_rcpf(r * r);   // -log2e/(2r^2)
    const float lsi = __builtin_amdgcn_logf(fmaf(0.5f, uin[s], 0.5f)); // log2(si)
    const float dy  = yc - sy;
    cy[s] = fmaf(nc[s] * dy, dy, lsi);
  }
  const float burn = fmaf(0.6f, u_burn[b], 0.2f);      // BURN_MIN + 0.6*u

  // Burn mask for 8 consecutive pixels (same row), reused across 3 channels.
  float bm[8];
#pragma unroll
  for (int j = 0; j < 8; ++j) {
    const float xc   = fmaf((float)(w0 + j), delta, -1.0f);
    const float dist = __builtin_amdgcn_sqrtf(fmaf(xc, xc, y2));
    const float ew   = __builtin_amdgcn_exp2f(fmaf(dist, 2.0f * LOG2E, -1.4f * LOG2E));
    const float ewn  = fmaf(ew, ew_scale, ew_bias);    // (ew - ew_min) * inv_range
    float lm = -3.0e38f;
#pragma unroll
    for (int s = 0; s < S; ++s) {
      const float t = xc - sx[s];
      lm = fmaxf(lm, fmaf(nc[s] * t, t, cy[s]));       // log2(spot_s)
    }
    const float spots = __builtin_amdgcn_exp2f(lm);
    // clamp(x,0,1) in one v_med3_f32
    bm[j] = __builtin_amdgcn_fmed3f(fmaxf(ewn, spots) * burn, 0.0f, 1.0f);
  }

  // out = clip(img * (1 - bm*(1-ds_c)), 0, 1): fma + mul-clamp (med3) per elem.
  const float k0 = 1.0f - 0.7f, k1 = 1.0f - 0.4f, k2 = 1.0f - 0.3f;
  fvec4 o;
#define APPLY(vv, k, j0, j1, j2, j3, dst_off)                                        \
  o.x = __builtin_amdgcn_fmed3f((vv).x * fmaf(-bm[j0], (k), 1.0f), 0.0f, 1.0f);      \
  o.y = __builtin_amdgcn_fmed3f((vv).y * fmaf(-bm[j1], (k), 1.0f), 0.0f, 1.0f);      \
  o.z = __builtin_amdgcn_fmed3f((vv).z * fmaf(-bm[j2], (k), 1.0f), 0.0f, 1.0f);      \
  o.w = __builtin_amdgcn_fmed3f((vv).w * fmaf(-bm[j3], (k), 1.0f), 0.0f, 1.0f);      \
  *reinterpret_cast<fvec4*>(out + base + (dst_off)) = o;

  APPLY(v0, k0, 0, 1, 2, 3, 0)
  APPLY(v1, k0, 4, 5, 6, 7, 4)
  APPLY(v2, k1, 0, 1, 2, 3, PLANE)
  APPLY(v3, k1, 4, 5, 6, 7, PLANE + 4)
  APPLY(v4, k2, 0, 1, 2, 3, 2 * PLANE)
  APPLY(v5, k2, 4, 5, 6, 7, 2 * PLANE + 4)
#undef APPLY
}

extern "C" void kernel_launch(void* const* d_in, const int* in_sizes, int n_in,
                              void* d_out, int out_size, void* d_ws, size_t ws_size,
                              hipStream_t stream) {
  const float* img         = (const float*)d_in[0];
  const float* u_xy        = (const float*)d_in[1];
  const float* u_radius    = (const float*)d_in[2];
  const float* u_intensity = (const float*)d_in[3];
  const float* u_burn      = (const float*)d_in[4];
  float* out = (float*)d_out;

  // ew min/max analytic: exp is monotone in dist.
  // min dist at grid point (±1/511, ±1/511), max at the corners (±1, ±1).
  const float delta = 2.0f / 511.0f;
  const float cmin  = fabsf(-1.0f + 255.0f * delta);   // ~= 1/511 in f32 linspace arithmetic
  const float dmin  = sqrtf(2.0f * cmin * cmin);
  const float dmax  = sqrtf(2.0f);
  const float ew_min = expf(2.0f * (dmin - 0.7f));
  const float ew_max = expf(2.0f * (dmax - 0.7f));
  const float inv_range = 1.0f / (ew_max - ew_min + 1e-6f);
  const float ew_bias = -ew_min * inv_range;

  dim3 grid(B * BLOCKS_PER_BATCH);  // 4096 blocks
  dim3 block(256);
  pizza_burn_kernel<<<grid, block, 0, stream>>>(img, u_xy, u_radius, u_intensity,
                                                u_burn, out, inv_range, ew_bias);
}

// Round 7
// 180.739 us; speedup vs baseline: 1.0080x; 1.0080x over previous
//
#include <hip/hip_runtime.h>
#include <math.h>

// PizzaBurningEffect: out = clip(img * (1 - bm*(1-dark_scale_c)), 0, 1)
// bm = clip(max(ew_norm, max_s spot_s) * burn, 0, 1), shared across C=3 channels.
//
// R6 post-mortem: 4 structurally different kernels all pin at 58-60us =
// the poison-fill's own duration. Theory: the timed window inherits the
// L3 dirty-poison drain (~260MB) -> kernel is externally BW-starved.
// This round is the clean discriminator: 4px/thread, ~55 natural VGPR
// (no launch_bounds cap -> no spill risk), 3 hoisted 16B loads/thread,
// perfect 1KB/wave coalescing, med3 clamps. If still ~59us -> declare
// environmental roofline.

namespace {
constexpr int B = 32, C = 3, H = 512, W = 512, S = 8;
constexpr int PLANE = H * W;                            // 262144
constexpr int BLOCKS_PER_BATCH = PLANE / 4 / 256;       // 256 blocks/batch
constexpr float LOG2E = 1.4426950408889634f;
typedef float fvec4 __attribute__((ext_vector_type(4)));
}

__global__ __launch_bounds__(256) void pizza_burn_kernel(
    const float* __restrict__ img,
    const float* __restrict__ u_xy,
    const float* __restrict__ u_radius,
    const float* __restrict__ u_intensity,
    const float* __restrict__ u_burn,
    float* __restrict__ out,
    const float ew_scale, const float ew_bias)
{
  // b is wave-uniform (derived from blockIdx only) -> spot params scalarize.
  const int b    = blockIdx.x >> 8;                         // 256 blocks per batch
  const int pix4 = ((blockIdx.x & 255) << 8) | threadIdx.x; // 0..65535
  const int h    = pix4 >> 7;             // 128 float4 per row of 512
  const int w0   = (pix4 & 127) << 2;     // starting column of this float4

  // Issue all 3 channel loads first; 48B/thread in flight under mask compute.
  const size_t base = (size_t)b * (C * PLANE) + (size_t)h * W + w0;
  const fvec4 v0 = *reinterpret_cast<const fvec4*>(img + base);
  const fvec4 v1 = *reinterpret_cast<const fvec4*>(img + base + PLANE);
  const fvec4 v2 = *reinterpret_cast<const fvec4*>(img + base + 2 * PLANE);

  const float delta = 2.0f / 511.0f;
  const float yc = fmaf((float)h, delta, -1.0f);
  const float y2 = yc * yc;

  // Per-batch spot params (b uniform -> scalar loads). Row-folded:
  // lm_s(x) = nc_s*(xc-sx_s)^2 + cy_s,  cy_s = nc_s*(yc-sy_s)^2 + log2(si_s).
  const float* uxy = u_xy        + (size_t)b * S * 2;
  const float* urd = u_radius    + (size_t)b * S;
  const float* uin = u_intensity + (size_t)b * S;
  float sx[S], nc[S], cy[S];
#pragma unroll
  for (int s = 0; s < S; ++s) {
    sx[s] = fmaf(2.0f, uxy[2 * s + 0], -1.0f);
    const float sy = fmaf(2.0f, uxy[2 * s + 1], -1.0f);
    const float r  = fmaf(0.15f, urd[s], 0.05f);
    nc[s] = (-0.5f * LOG2E) * __builtin_amdgcn_rcpf(r * r);   // -log2e/(2r^2)
    const float lsi = __builtin_amdgcn_logf(fmaf(0.5f, uin[s], 0.5f)); // log2(si)
    const float dy  = yc - sy;
    cy[s] = fmaf(nc[s] * dy, dy, lsi);
  }
  const float burn = fmaf(0.6f, u_burn[b], 0.2f);      // BURN_MIN + 0.6*u

  // Burn mask for 4 consecutive pixels (same row), reused across 3 channels.
  float bm[4];
#pragma unroll
  for (int j = 0; j < 4; ++j) {
    const float xc   = fmaf((float)(w0 + j), delta, -1.0f);
    const float dist = __builtin_amdgcn_sqrtf(fmaf(xc, xc, y2));
    const float ew   = __builtin_amdgcn_exp2f(fmaf(dist, 2.0f * LOG2E, -1.4f * LOG2E));
    const float ewn  = fmaf(ew, ew_scale, ew_bias);    // (ew - ew_min) * inv_range
    float lm = -3.0e38f;
#pragma unroll
    for (int s = 0; s < S; ++s) {
      const float t = xc - sx[s];
      lm = fmaxf(lm, fmaf(nc[s] * t, t, cy[s]));       // log2(spot_s)
    }
    const float spots = __builtin_amdgcn_exp2f(lm);
    bm[j] = __builtin_amdgcn_fmed3f(fmaxf(ewn, spots) * burn, 0.0f, 1.0f);
  }

  // out = clip(img * (1 - bm*(1-ds_c)), 0, 1): fma + mul + med3 per element.
  const float k0 = 1.0f - 0.7f, k1 = 1.0f - 0.4f, k2 = 1.0f - 0.3f;
  fvec4 o;
#define APPLY(vv, k, dst_off)                                                   \
  o.x = __builtin_amdgcn_fmed3f((vv).x * fmaf(-bm[0], (k), 1.0f), 0.0f, 1.0f);  \
  o.y = __builtin_amdgcn_fmed3f((vv).y * fmaf(-bm[1], (k), 1.0f), 0.0f, 1.0f);  \
  o.z = __builtin_amdgcn_fmed3f((vv).z * fmaf(-bm[2], (k), 1.0f), 0.0f, 1.0f);  \
  o.w = __builtin_amdgcn_fmed3f((vv).w * fmaf(-bm[3], (k), 1.0f), 0.0f, 1.0f);  \
  *reinterpret_cast<fvec4*>(out + base + (dst_off)) = o;

  APPLY(v0, k0, 0)
  APPLY(v1, k1, PLANE)
  APPLY(v2, k2, 2 * PLANE)
#undef APPLY
}

extern "C" void kernel_launch(void* const* d_in, const int* in_sizes, int n_in,
                              void* d_out, int out_size, void* d_ws, size_t ws_size,
                              hipStream_t stream) {
  const float* img         = (const float*)d_in[0];
  const float* u_xy        = (const float*)d_in[1];
  const float* u_radius    = (const float*)d_in[2];
  const float* u_intensity = (const float*)d_in[3];
  const float* u_burn      = (const float*)d_in[4];
  float* out = (float*)d_out;

  // ew min/max analytic: exp is monotone in dist.
  // min dist at grid point (±1/511, ±1/511), max at the corners (±1, ±1).
  const float delta = 2.0f / 511.0f;
  const float cmin  = fabsf(-1.0f + 255.0f * delta);   // ~= 1/511 in f32 linspace arithmetic
  const float dmin  = sqrtf(2.0f * cmin * cmin);
  const float dmax  = sqrtf(2.0f);
  const float ew_min = expf(2.0f * (dmin - 0.7f));
  const float ew_max = expf(2.0f * (dmax - 0.7f));
  const float inv_range = 1.0f / (ew_max - ew_min + 1e-6f);
  const float ew_bias = -ew_min * inv_range;

  dim3 grid(B * BLOCKS_PER_BATCH);  // 8192 blocks
  dim3 block(256);
  pizza_burn_kernel<<<grid, block, 0, stream>>>(img, u_xy, u_radius, u_intensity,
                                                u_burn, out, inv_range, ew_bias);
}